// Round 2
// baseline (108.378 us; speedup 1.0000x reference)
//
#include <hip/hip_runtime.h>
#include <cmath>

#define NCLUST   64
#define TSTEPS   32
#define BATCH    64
#define DIM      4096
#define NTHREADS 1024
#define NPT      4                  // neurons per thread, strided by 1024
#define NWAVES   (NTHREADS / 64)
#define REFRAC   2

// One block per batch row. Thread tid owns neurons d = tid + j*1024; since
// 1024 % 64 == 0 all of them are in cluster (tid & 63) == lane. State in f64
// so we track the reference trajectory far inside the demonstrated ~4e-3
// spike margin. Per step: phase 1 (apply prev cascade, decay, spike, LDS
// integer-atomic cluster counts, store outputs) -> barrier -> phase 2 (every
// wave computes 4 cascade entries via shuffle-tree dot products) -> barrier.
__global__ __launch_bounds__(NTHREADS)
void alif_fwd(const float* __restrict__ x_in,      // (T,B,D)
              const float* __restrict__ threshold, // (D)
              const float* __restrict__ bm_raw,    // scalar
              const float* __restrict__ bs_raw,    // scalar
              const float* __restrict__ nw,        // (NC,NC)
              const float* __restrict__ gain,      // (NC)
              float* __restrict__ out_s,           // (T,B,D)
              float* __restrict__ out_v)           // (T,B,D)
{
    __shared__ double       sW[NCLUST * NCLUST];   // sW[c'][c] = sigmoid(nw[c'][c])
    __shared__ double       sGain[NCLUST];
    __shared__ double       sCasc[NCLUST];
    __shared__ unsigned int sCnt[2][NCLUST];       // double-buffered integer counts

    const int tid  = threadIdx.x;
    const int lane = tid & 63;
    const int wav  = tid >> 6;
    const int b    = blockIdx.x;

    for (int i = tid; i < NCLUST * NCLUST; i += NTHREADS) {
        double w = (double)nw[i];
        sW[i] = 1.0 / (1.0 + exp(-w));             // row-major, consecutive per lane
    }
    if (wav == 0) {
        sGain[lane]   = (double)gain[lane];
        sCasc[lane]   = 0.0;
        sCnt[0][lane] = 0u;
        sCnt[1][lane] = 0u;
    }

    const double beta_m = 1.0 / (1.0 + exp(-(double)bm_raw[0]));
    const double beta_s = 1.0 / (1.0 + exp(-(double)bs_raw[0]));
    const double ombm   = 1.0 - beta_m;
    const double vreset = (double)(-0.1f);         // reference materializes V_RESET as f32

    double v[NPT], isyn[NPT], th[NPT];
    int refrac[NPT];
#pragma unroll
    for (int j = 0; j < NPT; j++) {
        v[j] = 0.0; isyn[j] = 0.0; refrac[j] = 0;
        th[j] = (double)threshold[tid + j * NTHREADS];
    }

    const size_t strideT = (size_t)BATCH * DIM;
    const float* xb = x_in + (size_t)b * DIM + tid;
    float* sp_ptr = out_s + (size_t)b * DIM + tid;
    float* vp_ptr = out_v + (size_t)b * DIM + tid;

    // depth-2 software prefetch: xA holds x[2k], xB holds x[2k+1]
    float xA[NPT], xB[NPT];
#pragma unroll
    for (int j = 0; j < NPT; j++) {
        xA[j] = xb[j * NTHREADS];
        xB[j] = xb[strideT + j * NTHREADS];
    }

    __syncthreads();

#define STEP(T_, XC, P)                                                      \
    {                                                                        \
        const double casc = sCasc[lane];                                     \
        unsigned int cnt = 0;                                                \
        float s_[NPT];                                                       \
        _Pragma("unroll")                                                    \
        for (int j = 0; j < NPT; j++) {                                      \
            double is = isyn[j] + casc;          /* i_syn += cascade (prev) */ \
            is = beta_s * is + (double)XC[j];    /* decay + input          */ \
            double vn = beta_m * v[j] + ombm * is;                           \
            double vv = (refrac[j] > 0) ? vreset : vn;                       \
            bool sp = (vv >= th[j]);                                         \
            s_[j] = sp ? 1.0f : 0.0f;                                        \
            cnt += sp ? 1u : 0u;                                             \
            v[j] = sp ? (vv - th[j]) : vv;                                   \
            refrac[j] = sp ? REFRAC : ((refrac[j] > 0) ? refrac[j] - 1 : 0); \
            isyn[j] = is;                                                    \
        }                                                                    \
        if (cnt) atomicAdd(&sCnt[P][lane], cnt);                             \
        _Pragma("unroll")                                                    \
        for (int j = 0; j < NPT; j++) {                                      \
            sp_ptr[j * NTHREADS] = s_[j];                                    \
            vp_ptr[j * NTHREADS] = (float)v[j];                              \
        }                                                                    \
        sp_ptr += strideT; vp_ptr += strideT;                                \
        if ((T_) + 2 < TSTEPS) {                                             \
            const float* xt2 = xb + (size_t)((T_) + 2) * strideT;            \
            _Pragma("unroll")                                                \
            for (int j = 0; j < NPT; j++) XC[j] = xt2[j * NTHREADS];         \
        }                                                                    \
        __syncthreads();                                                     \
        {                                                                    \
            const double cf = (double)sCnt[P][lane] * (1.0 / 64.0);          \
            const int c0 = wav * 4;                                          \
            double q0 = cf * sW[(c0 + 0) * NCLUST + lane];                   \
            double q1 = cf * sW[(c0 + 1) * NCLUST + lane];                   \
            double q2 = cf * sW[(c0 + 2) * NCLUST + lane];                   \
            double q3 = cf * sW[(c0 + 3) * NCLUST + lane];                   \
            if (wav == 0) sCnt[P ^ 1][lane] = 0u;  /* reset other slot */    \
            _Pragma("unroll")                                                \
            for (int m = 1; m < 64; m <<= 1) {                               \
                q0 += __shfl_xor(q0, m, 64);                                 \
                q1 += __shfl_xor(q1, m, 64);                                 \
                q2 += __shfl_xor(q2, m, 64);                                 \
                q3 += __shfl_xor(q3, m, 64);                                 \
            }                                                                \
            if (lane == 0) {                                                 \
                sCasc[c0 + 0] = q0 * sGain[c0 + 0];                          \
                sCasc[c0 + 1] = q1 * sGain[c0 + 1];                          \
                sCasc[c0 + 2] = q2 * sGain[c0 + 2];                          \
                sCasc[c0 + 3] = q3 * sGain[c0 + 3];                          \
            }                                                                \
        }                                                                    \
        __syncthreads();                                                     \
    }

    for (int k = 0; k < TSTEPS / 2; k++) {
        const int t0 = 2 * k;
        STEP(t0,     xA, 0)
        STEP(t0 + 1, xB, 1)
    }
#undef STEP
}

extern "C" void kernel_launch(void* const* d_in, const int* in_sizes, int n_in,
                              void* d_out, int out_size, void* d_ws, size_t ws_size,
                              hipStream_t stream) {
    const float* x  = (const float*)d_in[0];
    const float* th = (const float*)d_in[1];
    const float* bm = (const float*)d_in[2];
    const float* bs = (const float*)d_in[3];
    const float* nw = (const float*)d_in[4];
    const float* gn = (const float*)d_in[5];
    float* out_s = (float*)d_out;
    float* out_v = out_s + (size_t)TSTEPS * BATCH * DIM;

    hipLaunchKernelGGL(alif_fwd, dim3(BATCH), dim3(NTHREADS), 0, stream,
                       x, th, bm, bs, nw, gn, out_s, out_v);
}

// Round 3
// 57.895 us; speedup vs baseline: 1.8720x; 1.8720x over previous
//
#include <hip/hip_runtime.h>
#include <cmath>

#define NCLUST   64
#define TSTEPS   32
#define BATCH    64
#define DIM      4096
#define NTHREADS 1024
#define NPT      4                  // neurons per thread, strided by 1024
#define REFRAC   2

// Raw barrier: LDS-only drain (lgkmcnt), global stores keep floating.
// Rule #18 discipline: memory clobber + sched_barrier fences on both sides.
#define BAR()                                                   \
    do {                                                        \
        __builtin_amdgcn_sched_barrier(0);                      \
        asm volatile("s_waitcnt lgkmcnt(0)" ::: "memory");      \
        __builtin_amdgcn_s_barrier();                           \
        __builtin_amdgcn_sched_barrier(0);                      \
    } while (0)

// One block per batch row. Thread tid owns neurons d = tid + j*1024; since
// 1024 % 64 == 0 they all live in cluster (tid & 63) == lane. State in f64
// (tracks the f64 trajectory; demonstrated spike margin ~4e-3).
// Per step: phase 1 (all waves: apply prev cascade, decay, spike, one LDS
// integer atomic per wave, issue output stores) -> BAR -> phase 2 (wave 0
// alone does the 64x64 matvec; wave 1 resets the other count slot) -> BAR.
__global__ __launch_bounds__(NTHREADS)
void alif_fwd(const float* __restrict__ x_in,      // (T,B,D)
              const float* __restrict__ threshold, // (D)
              const float* __restrict__ bm_raw,    // scalar
              const float* __restrict__ bs_raw,    // scalar
              const float* __restrict__ nw,        // (NC,NC)
              const float* __restrict__ gain,      // (NC)
              float* __restrict__ out_s,           // (T,B,D)
              float* __restrict__ out_v)           // (T,B,D)
{
    __shared__ double       sW[NCLUST * NCLUST];   // sW[c][c'] = sigmoid(nw[c][c']), c' consecutive
    __shared__ double       sGain[NCLUST];
    __shared__ double       sCasc[NCLUST];
    __shared__ unsigned int sCnt[2][NCLUST];       // double-buffered integer spike counts

    const int tid  = threadIdx.x;
    const int lane = tid & 63;
    const int wav  = tid >> 6;
    const int b    = blockIdx.x;

    for (int i = tid; i < NCLUST * NCLUST; i += NTHREADS) {
        double w = (double)nw[i];
        sW[i] = 1.0 / (1.0 + exp(-w));
    }
    if (wav == 0) {
        sGain[lane]   = (double)gain[lane];
        sCasc[lane]   = 0.0;
        sCnt[0][lane] = 0u;
        sCnt[1][lane] = 0u;
    }

    const double beta_m = 1.0 / (1.0 + exp(-(double)bm_raw[0]));
    const double beta_s = 1.0 / (1.0 + exp(-(double)bs_raw[0]));
    const double ombm   = 1.0 - beta_m;
    const double vreset = (double)(-0.1f);

    double v[NPT], isyn[NPT], th[NPT];
    int refrac[NPT];
#pragma unroll
    for (int j = 0; j < NPT; j++) {
        v[j] = 0.0; isyn[j] = 0.0; refrac[j] = 0;
        th[j] = (double)threshold[tid + j * NTHREADS];
    }

    const size_t strideT = (size_t)BATCH * DIM;
    const float* xb = x_in + (size_t)b * DIM + tid;
    float* sp_ptr = out_s + (size_t)b * DIM + tid;
    float* vp_ptr = out_v + (size_t)b * DIM + tid;

    // depth-2 software prefetch: xA holds x[2k], xB holds x[2k+1]
    float xA[NPT], xB[NPT];
#pragma unroll
    for (int j = 0; j < NPT; j++) {
        xA[j] = xb[j * NTHREADS];
        xB[j] = xb[strideT + j * NTHREADS];
    }

    __syncthreads();   // one-time init barrier (safe full drain, happens once)

#define STEP(T_, XC, P)                                                       \
    {                                                                         \
        const double casc = sCasc[lane];                                      \
        unsigned int cnt = 0;                                                 \
        float s_[NPT];                                                        \
        _Pragma("unroll")                                                     \
        for (int j = 0; j < NPT; j++) {                                       \
            double is = isyn[j] + casc;           /* += cascade (prev step) */\
            is = beta_s * is + (double)XC[j];                                 \
            double vn = beta_m * v[j] + ombm * is;                            \
            double vv = (refrac[j] > 0) ? vreset : vn;                        \
            bool sp = (vv >= th[j]);                                          \
            s_[j] = sp ? 1.0f : 0.0f;                                         \
            cnt += sp ? 1u : 0u;                                              \
            v[j] = sp ? (vv - th[j]) : vv;                                    \
            refrac[j] = sp ? REFRAC : ((refrac[j] > 0) ? refrac[j] - 1 : 0);  \
            isyn[j] = is;                                                     \
        }                                                                     \
        atomicAdd(&sCnt[P][lane], cnt);                                       \
        _Pragma("unroll")                                                     \
        for (int j = 0; j < NPT; j++) {                                       \
            sp_ptr[j * NTHREADS] = s_[j];                                     \
            vp_ptr[j * NTHREADS] = (float)v[j];                               \
        }                                                                     \
        sp_ptr += strideT; vp_ptr += strideT;                                 \
        if ((T_) + 2 < TSTEPS) {                                              \
            const float* xt2 = xb + (size_t)((T_) + 2) * strideT;             \
            _Pragma("unroll")                                                 \
            for (int j = 0; j < NPT; j++) XC[j] = xt2[j * NTHREADS];          \
        }                                                                     \
        BAR();                                                                \
        if (wav == 0) {                                                       \
            /* 64x64 matvec: lane = output cluster c'; serial over c,      */ \
            /* 4-way interleaved f64 accumulators; counts via uint4 bcast. */ \
            double a0 = 0.0, a1 = 0.0, a2 = 0.0, a3 = 0.0;                    \
            _Pragma("unroll")                                                 \
            for (int c = 0; c < NCLUST; c += 4) {                             \
                uint4 c4 = *(const uint4*)&sCnt[P][c];                        \
                a0 += (double)c4.x * sW[(c + 0) * NCLUST + lane];             \
                a1 += (double)c4.y * sW[(c + 1) * NCLUST + lane];             \
                a2 += (double)c4.z * sW[(c + 2) * NCLUST + lane];             \
                a3 += (double)c4.w * sW[(c + 3) * NCLUST + lane];             \
            }                                                                 \
            double acc = ((a0 + a1) + (a2 + a3)) * (1.0 / 64.0);              \
            sCasc[lane] = acc * sGain[lane];                                  \
        } else if (wav == 1) {                                                \
            sCnt[P ^ 1][lane] = 0u;   /* reset slot for step T_+1 */          \
        }                                                                     \
        BAR();                                                                \
    }

    for (int k = 0; k < TSTEPS / 2; k++) {
        const int t0 = 2 * k;
        STEP(t0,     xA, 0)
        STEP(t0 + 1, xB, 1)
    }
#undef STEP
}

extern "C" void kernel_launch(void* const* d_in, const int* in_sizes, int n_in,
                              void* d_out, int out_size, void* d_ws, size_t ws_size,
                              hipStream_t stream) {
    const float* x  = (const float*)d_in[0];
    const float* th = (const float*)d_in[1];
    const float* bm = (const float*)d_in[2];
    const float* bs = (const float*)d_in[3];
    const float* nw = (const float*)d_in[4];
    const float* gn = (const float*)d_in[5];
    float* out_s = (float*)d_out;
    float* out_v = out_s + (size_t)TSTEPS * BATCH * DIM;

    hipLaunchKernelGGL(alif_fwd, dim3(BATCH), dim3(NTHREADS), 0, stream,
                       x, th, bm, bs, nw, gn, out_s, out_v);
}